// Round 9
// baseline (116.580 us; speedup 1.0000x reference)
//
#include <hip/hip_runtime.h>
#include <stdint.h>
#include <math.h>

// Soft-DTW forward, B=64, N=M=512, gamma=1 — probability-domain wavefront DP.
// R = d + softmin(a,b,c) carried as P = exp(-R): P_new = exp(-d)*(Pa+Pb+Pc)
// -> critical chain is dpp -> mul(rsc) -> cndmask -> fma -> fma.
// Scale: PER-LANE exponent E (P_true = x * 2^E), per-chunk renorm to 2^-10;
// lane->lane DPP handoff rescaled by rsc = 2^(E_{l-1}-E_l); inter-wave
// handoff reconciled exactly via v_ldexp_f32 + lane-63-published per-chunk E.
//
// ROUND 8/9 DELTA (only change vs round 7; round 8 never ran — infra failure):
// the per-chunk __syncthreads() is replaced with raw `s_waitcnt lgkmcnt(0);
// s_barrier`. __syncthreads emits s_waitcnt vmcnt(0) which drained the 11
// just-issued prefetch loads at every barrier — 54 VMEM-queue collapses per
// kernel; counters show we run at the resulting memory duty-cycle limit
// (430 GB/s on 64 CUs = 6.4 B/cy/CU). Cross-wave comms are LDS-only
// (lgkmcnt covers them); in-flight loads are wave-private reads of constant
// D, safe to carry across the barrier.
//
// 64 blocks (1/batch) x 4 waves. Lane l of wave w owns DP rows 128w+2l+1/+2.
// At wave-local step t, lane computes column c = t-l for both rows.

namespace {
constexpr int NWAVE = 4;
constexpr int DELTA = 96;                     // wave-to-wave step offset
constexpr int MCOLS = 512;
constexpr int LOCAL = MCOLS + 63;             // 575 steps per wave
constexpr int NCHUNK = 54;                    // 54*16=864 >= 3*96+575=863, even
constexpr int BROW = 608;                     // live 0..511, trash 544..607
constexpr float LN2 = 0.69314718055994530942f;
constexpr float L2E = 1.44269504088896340736f;
}

using f4 = __attribute__((ext_vector_type(4))) float;
using u32x4 = __attribute__((ext_vector_type(4))) unsigned int;

__device__ __forceinline__ float dpp_shr1(float v) {
  // lane n <- lane n-1 (wave_shr:1); lane 0 reads 0 (bound_ctrl) = P(INF)
  return __int_as_float(__builtin_amdgcn_update_dpp(0, __float_as_int(v), 0x138, 0xf, 0xf, true));
}
__device__ __forceinline__ int dpp_shr1_i(int v) {
  return __builtin_amdgcn_update_dpp(0, v, 0x138, 0xf, 0xf, true);
}
__device__ __forceinline__ float rdlane(float v, int lane) {
  return __int_as_float(__builtin_amdgcn_readlane(__float_as_int(v), lane));
}

// 16 DP steps over the current chunk. G = guarded (fill/drain) variant.
template <bool G>
__device__ __forceinline__ void steps16(
    const f4& q0, const f4& q1, const f4& q2, const f4& q3,
    const f4& q4, const f4& q5, const f4& q6,
    float e0, float e1, float e2, float e3,
    int t0, int l, int tid, bool isL0, float rsc, float curv,
    float* __restrict__ bwr,
    float& x1, float& x2, float& areg)
{
#pragma unroll
  for (int s = 0; s < 16; ++s) {
    const int c = t0 + s - l;
    const float d1 = (s < 4) ? q0[s & 3] : (s < 8) ? q1[s & 3]
                   : (s < 12) ? q2[s & 3] : q3[s & 3];
    const float d2 = (s < 4) ? q4[s & 3] : (s < 8) ? q5[s & 3]
                   : (s < 12) ? q6[s & 3]
                   : (s == 12 ? e0 : s == 13 ? e1 : s == 14 ? e2 : e3);
    // off-chain: exp(-d) = exp2(-d*log2e), inputs prefetched a chunk ahead
    const float k1 = __builtin_amdgcn_exp2f(d1 * -L2E);
    const float k2 = __builtin_amdgcn_exp2f(d2 * -L2E);
    float aa = areg;
    if (G) aa = (tid == 0 && c == 0) ? 1.0f : aa;  // P(R[0][0]=0)=1 seed
    const float k1s1 = k1 * (aa + x1);  // off-chain
    const float k2s2 = k2 * (x1 + x2);  // off-chain
    // chain: dpp -> mul -> cndmask -> fma -> fma
    const float bsh = dpp_shr1(x2) * rsc;           // lane l-1's x2, rescaled
    const float bb = isL0 ? rdlane(curv, s) : bsh;  // lane0: wave-boundary
    const float x1n = fmaf(k1, bb, k1s1);   // row i1: k1*(aa+x1+bb)
    const float x2n = fmaf(k2, x1n, k2s2);  // row i2: k2*(x1+x2+x1n)
    if (G) {
      const bool act = (unsigned)c < 512u;
      const int idx = act ? c : (int)(544u + ((unsigned)c & 63u));  // OOB->trash
      bwr[idx] = x2n;
      x1 = act ? x1n : x1;
      x2 = act ? x2n : x2;
    } else {
      bwr[c] = x2n;  // all lanes store; lane 63 (step c+63) writes last
      x1 = x1n;
      x2 = x2n;
    }
    areg = bb;  // next step's diagonal (incl. lane-0 boundary value)
  }
}

// Issue the 11 loads for the chunk starting at wave-local step T0N.
// Rows r1 (4x dwordx4) and r1+1 (3x dwordx4 + 4x dword: the scalar tail keeps
// the absolute-last-row quad from tripping the whole-access bounds check).
#define ISSUE(Q0, Q1, Q2, Q3, Q4, Q5, Q6, E0, E1, E2, E3, T0N) do {                 \
    const int st_ = (T0N) - l;                                                      \
    const int vo1_ = byte1 + (st_ << 2);                                            \
    const int vo2_ = vo1_ + 2048;                                                   \
    asm volatile("buffer_load_dwordx4 %0, %1, %2, 0 offen"           : "=v"(Q0) : "v"(vo1_), "s"(srd)); \
    asm volatile("buffer_load_dwordx4 %0, %1, %2, 0 offen offset:16" : "=v"(Q1) : "v"(vo1_), "s"(srd)); \
    asm volatile("buffer_load_dwordx4 %0, %1, %2, 0 offen offset:32" : "=v"(Q2) : "v"(vo1_), "s"(srd)); \
    asm volatile("buffer_load_dwordx4 %0, %1, %2, 0 offen offset:48" : "=v"(Q3) : "v"(vo1_), "s"(srd)); \
    asm volatile("buffer_load_dwordx4 %0, %1, %2, 0 offen"           : "=v"(Q4) : "v"(vo2_), "s"(srd)); \
    asm volatile("buffer_load_dwordx4 %0, %1, %2, 0 offen offset:16" : "=v"(Q5) : "v"(vo2_), "s"(srd)); \
    asm volatile("buffer_load_dwordx4 %0, %1, %2, 0 offen offset:32" : "=v"(Q6) : "v"(vo2_), "s"(srd)); \
    asm volatile("buffer_load_dword   %0, %1, %2, 0 offen offset:48" : "=v"(E0) : "v"(vo2_), "s"(srd)); \
    asm volatile("buffer_load_dword   %0, %1, %2, 0 offen offset:52" : "=v"(E1) : "v"(vo2_), "s"(srd)); \
    asm volatile("buffer_load_dword   %0, %1, %2, 0 offen offset:56" : "=v"(E2) : "v"(vo2_), "s"(srd)); \
    asm volatile("buffer_load_dword   %0, %1, %2, 0 offen offset:60" : "=v"(E3) : "v"(vo2_), "s"(srd)); \
} while (0)

// Wait for the current chunk's 11 loads (leave the 11 just-issued in flight).
// "+v" ties make the data dependence explicit -> consumers cannot hoist.
#define WAITQ(Q0, Q1, Q2, Q3, Q4, Q5, Q6, E0, E1, E2, E3)                           \
    asm volatile("s_waitcnt vmcnt(11)"                                              \
        : "+v"(Q0), "+v"(Q1), "+v"(Q2), "+v"(Q3), "+v"(Q4), "+v"(Q5),              \
          "+v"(Q6), "+v"(E0), "+v"(E1), "+v"(E2), "+v"(E3)::)

#define BODY(CQ0, CQ1, CQ2, CQ3, CQ4, CQ5, CQ6, CE0, CE1, CE2, CE3,                 \
             NQ0, NQ1, NQ2, NQ3, NQ4, NQ5, NQ6, NE0, NE1, NE2, NE3, MC) do {        \
    const int t0_ = 16 * (MC) - ow;                                                 \
    ISSUE(NQ0, NQ1, NQ2, NQ3, NQ4, NQ5, NQ6, NE0, NE1, NE2, NE3,                    \
          16 * ((MC) + 1) - ow);                                                    \
    WAITQ(CQ0, CQ1, CQ2, CQ3, CQ4, CQ5, CQ6, CE0, CE1, CE2, CE3);                   \
    if (t0_ >= 0 && t0_ < LOCAL) {                                                  \
      /* per-lane scale maintenance */                                              \
      const int ENpre_ = dpp_shr1_i(E);                                             \
      const bool inact_ = (x1 == 0.0f) && (x2 == 0.0f);                             \
      if (w > 0 && t0_ == 0) E = brdE[3];        /* whole-wave scale adoption */    \
      else if (inact_ && !isL0) E = ENpre_;      /* track left neighbor */          \
      float curv_ = 0.0f;                                                           \
      if (w > 0 && t0_ < 512) {                                                     \
        const int j_ = l & 15;                                                      \
        /* column t0+j finalized during writer chunk k+3 (j==0) or k+4 (j>0) */     \
        const int Eb_ = brdE[(t0_ >> 4) + (j_ ? 4 : 3)];                            \
        const int E0_ = __builtin_amdgcn_readfirstlane(E);                          \
        curv_ = ldexpf(brd[t0_ + j_], Eb_ - E0_);  /* exact reconcile, lane-0 scale */ \
      }                                                                             \
      if (l == 63) bwrE[t0_ >> 4] = E;           /* lane 63 makes final writes */   \
      const int EN2_ = dpp_shr1_i(E);                                               \
      int dE_ = EN2_ - E;                                                           \
      dE_ = dE_ < -126 ? -126 : (dE_ > 126 ? 126 : dE_);                            \
      const float rsc_ = __int_as_float((127 + dE_) << 23);                         \
      if (t0_ >= 64 && t0_ <= 496)                                                  \
        steps16<false>(CQ0, CQ1, CQ2, CQ3, CQ4, CQ5, CQ6, CE0, CE1, CE2, CE3,       \
                       t0_, l, tid, isL0, rsc_, curv_, bwr, x1, x2, areg);           \
      else                                                                          \
        steps16<true>(CQ0, CQ1, CQ2, CQ3, CQ4, CQ5, CQ6, CE0, CE1, CE2, CE3,        \
                      t0_, l, tid, isL0, rsc_, curv_, bwr, x1, x2, areg);            \
      /* per-lane renorm: recenter max(x1,x2) exponent to 2^-10 */                  \
      const int bx_ = (__float_as_int(x1) >> 23) & 255;                             \
      const int by_ = (__float_as_int(x2) >> 23) & 255;                             \
      int exm_ = bx_ > by_ ? bx_ : by_;                                             \
      int sh_ = (exm_ > 0) ? (117 - exm_) : 0;                                      \
      sh_ = sh_ < -110 ? -110 : sh_;                                                \
      const float sc_ = __int_as_float((127 + sh_) << 23);                          \
      x1 *= sc_; x2 *= sc_; areg *= sc_; E -= sh_;                                  \
    }                                                                               \
    /* barrier WITHOUT vmcnt drain: prefetch loads stay in flight (LDS comms  */    \
    /* are covered by lgkmcnt(0); in-flight loads are wave-private D reads).  */    \
    asm volatile("s_waitcnt lgkmcnt(0)\n\ts_barrier" ::: "memory");                 \
} while (0)

__global__ __launch_bounds__(256, 1) void sdtw_kernel(const float* __restrict__ D,
                                                      float* __restrict__ out) {
  static_assert(NCHUNK % 2 == 0, "loop is 2x unrolled");
  __shared__ float bnd[NWAVE + 1][BROW];  // [4] = dump row for wave 3
  __shared__ int bndE[NWAVE][36];         // per-wave per-chunk lane-63 scale E
  const int tid = threadIdx.x;
  const int w = tid >> 6, l = tid & 63, b = blockIdx.x;

  u32x4 srd;  // raw buffer descriptor over D: OOB reads return 0, never fault
  const uint64_t base = (uint64_t)(const void*)D;
  srd[0] = (unsigned)base;
  srd[1] = (unsigned)(base >> 32) & 0xffffu;  // stride=0
  srd[2] = 64u * 512u * 512u * 4u;            // num_records (bytes)
  srd[3] = 0x00020000u;

  const int r1 = (w << 7) + (l << 1);       // D row of i1 (0-based)
  const int byte1 = ((b << 9) + r1) << 11;  // (b*512 + r1) * 512 * 4
  const int ow = w * DELTA;
  const bool isL0 = (l == 0);

  float* __restrict__ bwr = &bnd[(w == NWAVE - 1) ? NWAVE : w][0];
  float* __restrict__ brd = &bnd[(w == 0) ? 0 : (w - 1)][0];
  int* __restrict__ bwrE = &bndE[w][0];
  int* __restrict__ brdE = &bndE[(w == 0) ? 0 : (w - 1)][0];

  float x1 = 0.0f, x2 = 0.0f, areg = 0.0f;  // P(INF) = 0
  int E = 0;                                // per-lane scale exponent

  // D double-buffers as named registers
  f4 qa0, qa1, qa2, qa3, qa4, qa5, qa6;
  f4 qb0, qb1, qb2, qb3, qb4, qb5, qb6;
  float ea0, ea1, ea2, ea3, eb0, eb1, eb2, eb3;

  ISSUE(qa0, qa1, qa2, qa3, qa4, qa5, qa6, ea0, ea1, ea2, ea3, -ow);  // chunk 0
  for (int mc = 0; mc < NCHUNK; mc += 2) {
    BODY(qa0, qa1, qa2, qa3, qa4, qa5, qa6, ea0, ea1, ea2, ea3,
         qb0, qb1, qb2, qb3, qb4, qb5, qb6, eb0, eb1, eb2, eb3, mc);
    BODY(qb0, qb1, qb2, qb3, qb4, qb5, qb6, eb0, eb1, eb2, eb3,
         qa0, qa1, qa2, qa3, qa4, qa5, qa6, ea0, ea1, ea2, ea3, mc + 1);
  }

  if (tid == NWAVE * 64 - 1) {
    // x2 * 2^E = exp(-R[512][512]);  v_log_f32 is log2
    const float Rv = -(__builtin_amdgcn_logf(x2) + (float)E);
    out[b] = Rv * LN2;
  }
}

extern "C" void kernel_launch(void* const* d_in, const int* in_sizes, int n_in,
                              void* d_out, int out_size, void* d_ws, size_t ws_size,
                              hipStream_t stream) {
  const float* D = (const float*)d_in[0];
  float* out = (float*)d_out;
  hipLaunchKernelGGL(sdtw_kernel, dim3(64), dim3(NWAVE * 64), 0, stream, D, out);
}

// Round 10
// 98.159 us; speedup vs baseline: 1.1877x; 1.1877x over previous
//
#include <hip/hip_runtime.h>
#include <stdint.h>
#include <math.h>

// Soft-DTW forward, B=64, N=M=512, gamma=1 — probability-domain wavefront DP.
// P = exp(-R): P_new = exp(-d)*(Pa+Pb+Pc); chain dpp->mul->cndmask->fma->fma.
// Per-lane scale E + per-chunk renorm + exact ldexp inter-wave reconcile
// (unchanged from the passing round-7 kernel).
//
// ROUND 10 DELTA (D-delivery only): per-lane row-strided buffer loads (64
// distinct cache lines per instruction -> ~2816 TA address-txns per chunk
// per CU, the measured ~5140cy/chunk stall) are replaced by COALESCED
// staging: each wave loads aligned 16-col blocks of its 128 rows with 8
// dwordx4 (4 lanes per 64B line -> 16 txns/instr, 512 txn/chunk/CU =
// intrinsic), packs to bf16 (v_cvt_pk_bf16_f32, RNE; d<1 -> |err|<=2^-9,
// accumulated ~0.06 << 10.16 threshold), stores into a wave-PRIVATE LDS
// ring (128 cols, 65-word row stride for bank spread; no barrier needed),
// and the DP loop reads skewed per-lane windows as 18 ds_read_b32/chunk
// (2-way banks = free). Stage issue at chunk top, vmcnt(0)+write after
// compute (T14). bnd/E/barrier machinery untouched.

namespace {
constexpr int NWAVE = 4;
constexpr int DELTA = 96;                     // wave-to-wave step offset
constexpr int MCOLS = 512;
constexpr int LOCAL = MCOLS + 63;             // 575 steps per wave
constexpr int NCHUNK = 54;                    // covers 3*96+575=863 steps
constexpr int BROW = 608;                     // bnd: live 0..511, trash 544..607
constexpr int RW = 65;                        // ring words/row: 64 data + 1 pad
constexpr float LN2 = 0.69314718055994530942f;
constexpr float L2E = 1.44269504088896340736f;
}

using f4 = __attribute__((ext_vector_type(4))) float;
using u32x4 = __attribute__((ext_vector_type(4))) unsigned int;

__device__ __forceinline__ float dpp_shr1(float v) {
  // lane n <- lane n-1 (wave_shr:1); lane 0 reads 0 (bound_ctrl) = P(INF)
  return __int_as_float(__builtin_amdgcn_update_dpp(0, __float_as_int(v), 0x138, 0xf, 0xf, true));
}
__device__ __forceinline__ int dpp_shr1_i(int v) {
  return __builtin_amdgcn_update_dpp(0, v, 0x138, 0xf, 0xf, true);
}
__device__ __forceinline__ float rdlane(float v, int lane) {
  return __int_as_float(__builtin_amdgcn_readlane(__float_as_int(v), lane));
}
// pack 2 f32 -> 1 u32 of 2 bf16 (RNE); D[15:0]=cvt(S0) = even col in low half
__device__ __forceinline__ void packw(const f4& g, uint32_t* p) {
  uint32_t w0, w1;
  asm("v_cvt_pk_bf16_f32 %0, %1, %2" : "=v"(w0) : "v"(g[0]), "v"(g[1]));
  asm("v_cvt_pk_bf16_f32 %0, %1, %2" : "=v"(w1) : "v"(g[2]), "v"(g[3]));
  p[0] = w0;
  p[1] = w1;
}

// compile-time word mux (k folds after unroll)
#define GETW(k) ((k)==0?W0:(k)==1?W1:(k)==2?W2:(k)==3?W3:(k)==4?W4:(k)==5?W5:(k)==6?W6:(k)==7?W7:W8)
#define GETV(k) ((k)==0?V0:(k)==1?V1:(k)==2?V2:(k)==3?V3:(k)==4?V4:(k)==5?V5:(k)==6?V6:(k)==7?V7:V8)

// 16 DP steps over the current chunk. G = guarded (fill/drain) variant.
// d-values come from the bf16 ring words W0..W8 (row 2l) / V0..V8 (row 2l+1):
// step s uses word (s+par)>>1, half (s+par)&1, par = l&1 (skew parity).
template <bool G>
__device__ __forceinline__ void steps16(
    uint32_t W0, uint32_t W1, uint32_t W2, uint32_t W3, uint32_t W4,
    uint32_t W5, uint32_t W6, uint32_t W7, uint32_t W8,
    uint32_t V0, uint32_t V1, uint32_t V2, uint32_t V3, uint32_t V4,
    uint32_t V5, uint32_t V6, uint32_t V7, uint32_t V8,
    int t0, int l, int tid, bool isL0, bool par, float rsc, float curv,
    float* __restrict__ bwr,
    float& x1, float& x2, float& areg)
{
#pragma unroll
  for (int s = 0; s < 16; ++s) {
    const int c = t0 + s - l;
    uint32_t wd, vd;
    bool sel;
    if ((s & 1) == 0) {          // even step: word s/2, half = par
      wd = GETW(s >> 1);
      vd = GETV(s >> 1);
      sel = par;
    } else {                     // odd step: word (s+par)>>1, half = !par
      wd = par ? GETW((s + 1) >> 1) : GETW(s >> 1);
      vd = par ? GETV((s + 1) >> 1) : GETV(s >> 1);
      sel = !par;
    }
    const float d1 = __uint_as_float(sel ? (wd & 0xffff0000u) : (wd << 16));
    const float d2 = __uint_as_float(sel ? (vd & 0xffff0000u) : (vd << 16));
    // off-chain: exp(-d) = exp2(-d*log2e)
    const float k1 = __builtin_amdgcn_exp2f(d1 * -L2E);
    const float k2 = __builtin_amdgcn_exp2f(d2 * -L2E);
    float aa = areg;
    if (G) aa = (tid == 0 && c == 0) ? 1.0f : aa;  // P(R[0][0]=0)=1 seed
    const float k1s1 = k1 * (aa + x1);  // off-chain
    const float k2s2 = k2 * (x1 + x2);  // off-chain
    // chain: dpp -> mul -> cndmask -> fma -> fma
    const float bsh = dpp_shr1(x2) * rsc;           // lane l-1's x2, rescaled
    const float bb = isL0 ? rdlane(curv, s) : bsh;  // lane0: wave-boundary
    const float x1n = fmaf(k1, bb, k1s1);   // row i1: k1*(aa+x1+bb)
    const float x2n = fmaf(k2, x1n, k2s2);  // row i2: k2*(x1+x2+x1n)
    if (G) {
      const bool act = (unsigned)c < 512u;
      const int idx = act ? c : (int)(544u + ((unsigned)c & 63u));  // OOB->trash
      bwr[idx] = x2n;
      x1 = act ? x1n : x1;   // garbage/NaN ring data for inactive c discarded here
      x2 = act ? x2n : x2;
    } else {
      bwr[c] = x2n;  // all lanes store; lane 63 (step c+63) writes last
      x1 = x1n;
      x2 = x2n;
    }
    areg = bb;  // next step's diagonal (incl. lane-0 boundary value)
  }
}

// Coalesced stage of col-block [CS, CS+16) for this wave's 128 rows:
// instr i, lane j: row 16i+(j>>2), 16B at col CS+(j&3)*4 -> 16 lines/instr.
#define STAGE_ISSUE(CS) do {                                                        \
    const int v0_ = voBase + ((CS) << 2);                                           \
    asm volatile("buffer_load_dwordx4 %0, %1, %2, 0 offen" : "=v"(g0) : "v"(v0_), "s"(srd));             \
    asm volatile("buffer_load_dwordx4 %0, %1, %2, 0 offen" : "=v"(g1) : "v"(v0_ + 1*32768), "s"(srd));   \
    asm volatile("buffer_load_dwordx4 %0, %1, %2, 0 offen" : "=v"(g2) : "v"(v0_ + 2*32768), "s"(srd));   \
    asm volatile("buffer_load_dwordx4 %0, %1, %2, 0 offen" : "=v"(g3) : "v"(v0_ + 3*32768), "s"(srd));   \
    asm volatile("buffer_load_dwordx4 %0, %1, %2, 0 offen" : "=v"(g4) : "v"(v0_ + 4*32768), "s"(srd));   \
    asm volatile("buffer_load_dwordx4 %0, %1, %2, 0 offen" : "=v"(g5) : "v"(v0_ + 5*32768), "s"(srd));   \
    asm volatile("buffer_load_dwordx4 %0, %1, %2, 0 offen" : "=v"(g6) : "v"(v0_ + 6*32768), "s"(srd));   \
    asm volatile("buffer_load_dwordx4 %0, %1, %2, 0 offen" : "=v"(g7) : "v"(v0_ + 7*32768), "s"(srd));   \
} while (0)

// vmcnt(0) is safe here: the 8 stage loads are the only in-flight VMEM.
#define STAGE_WRITE(CS) do {                                                        \
    asm volatile("s_waitcnt vmcnt(0)"                                               \
        : "+v"(g0), "+v"(g1), "+v"(g2), "+v"(g3),                                   \
          "+v"(g4), "+v"(g5), "+v"(g6), "+v"(g7)::);                                \
    const int ew_ = ((((CS) & 127) >> 1) + ((l & 3) << 1));                         \
    uint32_t* rp_ = &dring[w][l >> 2][ew_];                                         \
    packw(g0, rp_);            packw(g1, rp_ + 16 * RW);                            \
    packw(g2, rp_ + 32 * RW);  packw(g3, rp_ + 48 * RW);                            \
    packw(g4, rp_ + 64 * RW);  packw(g5, rp_ + 80 * RW);                            \
    packw(g6, rp_ + 96 * RW);  packw(g7, rp_ + 112 * RW);                           \
} while (0)

__global__ __launch_bounds__(256, 1) void sdtw_kernel(const float* __restrict__ D,
                                                      float* __restrict__ out) {
  __shared__ uint32_t dring[NWAVE][128][RW];  // per-wave PRIVATE bf16 col ring
  __shared__ float bnd[NWAVE + 1][BROW];      // [4] = dump row for wave 3
  __shared__ int bndE[NWAVE][36];             // per-wave per-chunk lane-63 E
  const int tid = threadIdx.x;
  const int w = tid >> 6, l = tid & 63, b = blockIdx.x;

  u32x4 srd;  // raw buffer descriptor over D
  const uint64_t base = (uint64_t)(const void*)D;
  srd[0] = (unsigned)base;
  srd[1] = (unsigned)(base >> 32) & 0xffffu;  // stride=0
  srd[2] = 64u * 512u * 512u * 4u;            // num_records (bytes)
  srd[3] = 0x00020000u;

  const int ow = w * DELTA;
  const bool isL0 = (l == 0);
  const bool par = (l & 1) != 0;
  // stage voffset base: row (128w + (l>>2)) of batch b, col-sub (l&3)*4
  const int voBase = (((b << 9) + (w << 7) + (l >> 2)) << 11) + ((l & 3) << 4);

  float* __restrict__ bwr = &bnd[(w == NWAVE - 1) ? NWAVE : w][0];
  float* __restrict__ brd = &bnd[(w == 0) ? 0 : (w - 1)][0];
  int* __restrict__ bwrE = &bndE[w][0];
  int* __restrict__ brdE = &bndE[(w == 0) ? 0 : (w - 1)][0];

  float x1 = 0.0f, x2 = 0.0f, areg = 0.0f;  // P(INF) = 0
  int E = 0;                                // per-lane scale exponent

  f4 g0, g1, g2, g3, g4, g5, g6, g7;  // staged f32 col-block

  // prologue: stage block [0,16) (wave-private ring, no barrier needed)
  STAGE_ISSUE(0);
  STAGE_WRITE(0);

  for (int mc = 0; mc < NCHUNK; ++mc) {
    const int t0_ = 16 * mc - ow;
    const bool doStage = (t0_ >= 0) && (t0_ <= 480);  // stages [t0+16,t0+32)
    if (doStage) STAGE_ISSUE(t0_ + 16);
    if (t0_ >= 0 && t0_ < LOCAL) {
      // ---- per-lane scale maintenance (unchanged) ----
      const int ENpre_ = dpp_shr1_i(E);
      const bool inact_ = (x1 == 0.0f) && (x2 == 0.0f);
      if (w > 0 && t0_ == 0) E = brdE[3];    // whole-wave scale adoption
      else if (inact_ && !isL0) E = ENpre_;  // track left neighbor
      float curv_ = 0.0f;
      if (w > 0 && t0_ < 512) {
        const int j_ = l & 15;
        const int Eb_ = brdE[(t0_ >> 4) + (j_ ? 4 : 3)];
        const int E0_ = __builtin_amdgcn_readfirstlane(E);
        curv_ = ldexpf(brd[t0_ + j_], Eb_ - E0_);  // exact reconcile
      }
      if (l == 63) bwrE[t0_ >> 4] = E;  // lane 63 makes the final writes
      const int EN2_ = dpp_shr1_i(E);
      int dE_ = EN2_ - E;
      dE_ = dE_ < -126 ? -126 : (dE_ > 126 ? 126 : dE_);
      const float rsc_ = __int_as_float((127 + dE_) << 23);
      // ---- ring reads: 9 words per row cover cols [t0-l, t0-l+16) ----
      const int e0_ = ((t0_ - l) & 127) >> 1;
      const uint32_t* q1_ = &dring[w][2 * l][0];
      const uint32_t* q2_ = &dring[w][2 * l + 1][0];
      const uint32_t W0 = q1_[(e0_ + 0) & 63], W1 = q1_[(e0_ + 1) & 63],
                     W2 = q1_[(e0_ + 2) & 63], W3 = q1_[(e0_ + 3) & 63],
                     W4 = q1_[(e0_ + 4) & 63], W5 = q1_[(e0_ + 5) & 63],
                     W6 = q1_[(e0_ + 6) & 63], W7 = q1_[(e0_ + 7) & 63],
                     W8 = q1_[(e0_ + 8) & 63];
      const uint32_t V0 = q2_[(e0_ + 0) & 63], V1 = q2_[(e0_ + 1) & 63],
                     V2 = q2_[(e0_ + 2) & 63], V3 = q2_[(e0_ + 3) & 63],
                     V4 = q2_[(e0_ + 4) & 63], V5 = q2_[(e0_ + 5) & 63],
                     V6 = q2_[(e0_ + 6) & 63], V7 = q2_[(e0_ + 7) & 63],
                     V8 = q2_[(e0_ + 8) & 63];
      if (t0_ >= 64 && t0_ <= 496)
        steps16<false>(W0, W1, W2, W3, W4, W5, W6, W7, W8,
                       V0, V1, V2, V3, V4, V5, V6, V7, V8,
                       t0_, l, tid, isL0, par, rsc_, curv_, bwr, x1, x2, areg);
      else
        steps16<true>(W0, W1, W2, W3, W4, W5, W6, W7, W8,
                      V0, V1, V2, V3, V4, V5, V6, V7, V8,
                      t0_, l, tid, isL0, par, rsc_, curv_, bwr, x1, x2, areg);
      // ---- per-lane renorm: recenter max(x1,x2) exponent to 2^-10 ----
      const int bx_ = (__float_as_int(x1) >> 23) & 255;
      const int by_ = (__float_as_int(x2) >> 23) & 255;
      int exm_ = bx_ > by_ ? bx_ : by_;
      int sh_ = (exm_ > 0) ? (117 - exm_) : 0;
      sh_ = sh_ < -110 ? -110 : sh_;
      const float sc_ = __int_as_float((127 + sh_) << 23);
      x1 *= sc_;
      x2 *= sc_;
      areg *= sc_;
      E -= sh_;
    }
    if (doStage) STAGE_WRITE(t0_ + 16);  // vmcnt(0) + cvt + ds_write (T14 late)
    // barrier for bnd only (dring is wave-private); no vmcnt drain needed
    asm volatile("s_waitcnt lgkmcnt(0)\n\ts_barrier" ::: "memory");
  }

  if (tid == NWAVE * 64 - 1) {
    // x2 * 2^E = exp(-R[512][512]);  v_log_f32 is log2
    const float Rv = -(__builtin_amdgcn_logf(x2) + (float)E);
    out[b] = Rv * LN2;
  }
}

extern "C" void kernel_launch(void* const* d_in, const int* in_sizes, int n_in,
                              void* d_out, int out_size, void* d_ws, size_t ws_size,
                              hipStream_t stream) {
  const float* D = (const float*)d_in[0];
  float* out = (float*)d_out;
  hipLaunchKernelGGL(sdtw_kernel, dim3(64), dim3(NWAVE * 64), 0, stream, D, out);
}